// Round 10
// baseline (177.951 us; speedup 1.0000x reference)
//
#include <hip/hip_runtime.h>
#include <hip/hip_bf16.h>
#include <stdint.h>

typedef __attribute__((ext_vector_type(4))) float f32x4;
typedef __attribute__((ext_vector_type(8))) short bf16x8;
typedef unsigned short u16;

#define T_TOK   2048
#define D_DIM   2048
#define DFF_DIM 1024
#define NEXP    8
#define TOPK    2
#define NROWS   (T_TOK * TOPK)   // 4096
#define BM      128
#define BK      64
#define MAX_MB  40
#define GRID_G  (16 * MAX_MB)    // 640 = 8 XCDs x 80

// ---- workspace layout ----
#define XB_OFF    65536
#define XB_BYTES  ((size_t)T_TOK * D_DIM * 2)                  // 8 MB
#define H_OFF     (XB_OFF + XB_BYTES)
#define H_BYTES   ((size_t)NROWS * DFF_DIM * 2)                // 8 MB
#define W1B_OFF   (H_OFF + H_BYTES)
#define W1B_BYTES ((size_t)NEXP * 2 * DFF_DIM * D_DIM * 2)     // 64 MB
#define W2B_OFF   (W1B_OFF + W1B_BYTES)
#define W2B_BYTES ((size_t)NEXP * D_DIM * DFF_DIM * 2)         // 32 MB
#define WS_NEED   (W2B_OFF + W2B_BYTES)                        // ~112 MB

// prep segmentation (chunks of 8 f32); exact powers of two -> no tails
#define W1_T   ((size_t)NEXP * 2 * DFF_DIM * D_DIM / 8)  // 2^22
#define W2_T   ((size_t)NEXP * D_DIM * DFF_DIM / 8)      // 2^21
#define X_T    ((size_t)T_TOK * D_DIM / 8)               // 2^19
#define W1_BLKS 1024   // 16 chunks/thread
#define W2_BLKS 512    // 16 chunks/thread
#define X_BLKS  256    // 8 chunks/thread
#define PREP_GRID (W1_BLKS + W2_BLKS + X_BLKS + 1)   // 1793 (last = routing)

#define PIN() asm volatile("" ::: "memory")
#define BAR_LGKM()                                                        \
    asm volatile("s_waitcnt lgkmcnt(0)" ::: "memory");                    \
    __builtin_amdgcn_s_barrier()

__device__ __forceinline__ u16 f2bf(float f) {
    __hip_bfloat16 h = __float2bfloat16(f);
    return *reinterpret_cast<u16*>(&h);
}

__device__ __forceinline__ void cvt8(const float* src, u16* dst) {
    f32x4 a = *(const f32x4*)src;
    f32x4 b = *(const f32x4*)(src + 4);
    bf16x8 v;
#pragma unroll
    for (int j = 0; j < 4; ++j) { v[j] = (short)f2bf(a[j]); v[j + 4] = (short)f2bf(b[j]); }
    *(bf16x8*)dst = v;
}

// 4 strided chunks, loads batched first (MLP=4, ~32 VGPR in flight)
__device__ __forceinline__ void cvt_quad(const float* __restrict__ src,
                                         u16* __restrict__ dst,
                                         size_t t, size_t str) {
    const float* p0 = src + t * 8;
    const float* p1 = src + (t + str) * 8;
    const float* p2 = src + (t + 2 * str) * 8;
    const float* p3 = src + (t + 3 * str) * 8;
    f32x4 a0 = *(const f32x4*)p0, b0 = *(const f32x4*)(p0 + 4);
    f32x4 a1 = *(const f32x4*)p1, b1 = *(const f32x4*)(p1 + 4);
    f32x4 a2 = *(const f32x4*)p2, b2 = *(const f32x4*)(p2 + 4);
    f32x4 a3 = *(const f32x4*)p3, b3 = *(const f32x4*)(p3 + 4);
    bf16x8 v0, v1, v2, v3;
#pragma unroll
    for (int j = 0; j < 4; ++j) {
        v0[j] = (short)f2bf(a0[j]); v0[j + 4] = (short)f2bf(b0[j]);
        v1[j] = (short)f2bf(a1[j]); v1[j + 4] = (short)f2bf(b1[j]);
        v2[j] = (short)f2bf(a2[j]); v2[j + 4] = (short)f2bf(b2[j]);
        v3[j] = (short)f2bf(a3[j]); v3[j + 4] = (short)f2bf(b3[j]);
    }
    *(bf16x8*)(dst + t * 8) = v0;
    *(bf16x8*)(dst + (t + str) * 8) = v1;
    *(bf16x8*)(dst + (t + 2 * str) * 8) = v2;
    *(bf16x8*)(dst + (t + 3 * str) * 8) = v3;
}

__device__ __forceinline__ void cvt_quad_zero(const float* __restrict__ src,
                                              u16* __restrict__ dst,
                                              float* __restrict__ zout,
                                              size_t t, size_t str) {
    cvt_quad(src, dst, t, str);
    f32x4 z = (f32x4){0.f, 0.f, 0.f, 0.f};
#pragma unroll
    for (int q = 0; q < 4; ++q) {
        *(f32x4*)(zout + (t + q * str) * 8) = z;
        *(f32x4*)(zout + (t + q * str) * 8 + 4) = z;
    }
}

__device__ __forceinline__ void gll16(const u16* gsrc, const u16* lds) {
    __builtin_amdgcn_global_load_lds(
        (const __attribute__((address_space(1))) uint32_t*)gsrc,
        (__attribute__((address_space(3))) uint32_t*)lds, 16, 0, 0);
}

// tile [128 rows][64 bf16=128B]; content XOR-swizzled by row
__device__ __forceinline__ bf16x8 lds_read8_swz(const u16* base, int row, int inner) {
    int off = row * 128 + (inner ^ ((row & 7) << 4));
    return *(const bf16x8*)((const char*)base + off);
}

__device__ __forceinline__ void route_body(const int* topk_ids, const float* topk_w,
                                           int* sched, int* row_token, float* row_w,
                                           int* cnt, int* off, int* cur) {
    const int tid = threadIdx.x;
    if (tid < NEXP) cnt[tid] = 0;
    __syncthreads();
    for (int p = tid; p < NROWS; p += blockDim.x)
        atomicAdd(&cnt[topk_ids[p]], 1);
    __syncthreads();
    if (tid == 0) {
        int acc = 0, mb = 0;
        for (int e = 0; e < NEXP; ++e) {
            off[e] = acc;
            int c = cnt[e];
            for (int m0 = 0; m0 < c; m0 += BM) {
                sched[1 + 3 * mb] = e;
                sched[2 + 3 * mb] = acc + m0;
                sched[3 + 3 * mb] = (c - m0 < BM) ? (c - m0) : BM;
                ++mb;
            }
            acc += c;
        }
        sched[0] = mb;
    }
    if (tid < NEXP) cur[tid] = 0;
    __syncthreads();
    for (int p = tid; p < NROWS; p += blockDim.x) {
        int e = topk_ids[p];
        int slot = off[e] + atomicAdd(&cur[e], 1);
        row_token[slot] = p / TOPK;
        row_w[slot]     = topk_w[p];
    }
}

// ---------------- prepass: segmented, branch-free, MLP=4 ---------------------
__global__ __launch_bounds__(256)
void prep_kernel(const float* __restrict__ w1, const float* __restrict__ w2,
                 const float* __restrict__ X,
                 u16* __restrict__ w1b, u16* __restrict__ w2b,
                 u16* __restrict__ Xb, float* __restrict__ out,
                 const int* __restrict__ topk_ids,
                 const float* __restrict__ topk_w,
                 int* __restrict__ sched, int* __restrict__ row_token,
                 float* __restrict__ row_w) {
    const int b = blockIdx.x;
    if (b >= W1_BLKS + W2_BLKS + X_BLKS) {   // routing-only block
        __shared__ int cnt[NEXP], off[NEXP], cur[NEXP];
        route_body(topk_ids, topk_w, sched, row_token, row_w, cnt, off, cur);
        return;
    }
    if (b < W1_BLKS) {
        const size_t STR = (size_t)W1_BLKS * 256;
        size_t t = (size_t)b * 256 + threadIdx.x;
#pragma unroll
        for (int o = 0; o < 4; ++o) {       // 16 chunks = 4 quads
            cvt_quad(w1, w1b, t, STR);
            t += 4 * STR;
        }
    } else if (b < W1_BLKS + W2_BLKS) {
        const size_t STR = (size_t)W2_BLKS * 256;
        size_t t = (size_t)(b - W1_BLKS) * 256 + threadIdx.x;
#pragma unroll
        for (int o = 0; o < 4; ++o) {       // 16 chunks
            cvt_quad(w2, w2b, t, STR);
            t += 4 * STR;
        }
    } else {
        const size_t STR = (size_t)X_BLKS * 256;
        size_t t = (size_t)(b - W1_BLKS - W2_BLKS) * 256 + threadIdx.x;
#pragma unroll
        for (int o = 0; o < 2; ++o) {       // 8 chunks
            cvt_quad_zero(X, Xb, out, t, STR);
            t += 4 * STR;
        }
    }
}

// XCD map: blocks sharing a B-tile (same e,n0; different m0) land on ONE XCD.
#define DECODE_BLOCK()                                                    \
    const int bid   = blockIdx.x;                                         \
    const int xcd   = bid & 7;                                            \
    const int local = bid >> 3;            /* 0..79 */                    \
    const int n0h   = local / MAX_MB;      /* 0..1  */                    \
    const int mb    = local - n0h * MAX_MB;                               \
    const int n0i   = xcd * 2 + n0h;       /* 0..15 */                    \
    if (mb >= sched[0]) return;                                           \
    const int e    = sched[1 + 3 * mb];                                   \
    const int m0   = sched[2 + 3 * mb];                                   \
    const int mlen = sched[3 + 3 * mb]

#define GLL8(k0)                                                          \
    _Pragma("unroll") for (int i = 0; i < 4; ++i)                         \
        gll16(asrc[i] + (k0), &lA[aoff[i]]);                              \
    _Pragma("unroll") for (int i = 0; i < 4; ++i)                         \
        gll16(bsrc[i] + (k0), &lB[aoff[i]]);

// ---------------- GEMM1 fast: gathered Xb @ w1b_e^T, silu*up -> H ------------
__global__ __launch_bounds__(256, 3)
void gemm1p_kernel(const u16* __restrict__ Xb, const u16* __restrict__ w1b,
                   const int* __restrict__ sched, const int* __restrict__ row_token,
                   u16* __restrict__ H) {
    __shared__ u16 lA[BM * BK];   // 16KB, gll (linear dest, pre-swz src)
    __shared__ u16 lB[BM * BK];   // 16KB, gll

    DECODE_BLOCK();
    const int n0 = n0i * 64;

    const int tid  = threadIdx.x;
    const int lane = tid & 63;
    const int wave = tid >> 6;
    const int wm = wave >> 1, wn = wave & 1;
    const int lr = lane & 15, lk = lane >> 4;

    const u16* asrc[4];
    const u16* bsrc[4];
    int aoff[4];
#pragma unroll
    for (int i = 0; i < 4; ++i) {
        int R = i * 32 + wave * 8 + (lane >> 3);
        int grow = m0 + R; if (grow > NROWS - 1) grow = NROWS - 1;
        int tok = row_token[grow];
        int c8 = ((lane & 7) ^ (R & 7)) * 8;
        asrc[i] = Xb + (size_t)tok * D_DIM + c8;
        int gr = (R < 64) ? (n0 + R) : (DFF_DIM + n0 + (R - 64));
        bsrc[i] = w1b + ((size_t)e * (2 * DFF_DIM) + gr) * D_DIM + c8;
        aoff[i] = i * 2048 + wave * 512;
    }

    f32x4 accg[4][2], accu[4][2];
#pragma unroll
    for (int m = 0; m < 4; ++m)
#pragma unroll
        for (int n = 0; n < 2; ++n) {
            accg[m][n] = (f32x4){0.f, 0.f, 0.f, 0.f};
            accu[m][n] = (f32x4){0.f, 0.f, 0.f, 0.f};
        }

    const int KT = D_DIM / BK;   // 32
    for (int kt = 0; kt < KT; ++kt) {
        GLL8(kt * BK);
        __syncthreads();   // drains glls (vmcnt 0)
#pragma unroll
        for (int ks = 0; ks < 2; ++ks) {
            const int inner = ks * 64 + lk * 16;
            bf16x8 af[4], bg[2], bu[2];
#pragma unroll
            for (int m = 0; m < 4; ++m)
                af[m] = lds_read8_swz(lA, wm * 64 + m * 16 + lr, inner);
#pragma unroll
            for (int n = 0; n < 2; ++n) {
                bg[n] = lds_read8_swz(lB, wn * 32 + n * 16 + lr, inner);
                bu[n] = lds_read8_swz(lB, 64 + wn * 32 + n * 16 + lr, inner);
            }
#pragma unroll
            for (int m = 0; m < 4; ++m)
#pragma unroll
                for (int n = 0; n < 2; ++n) {
                    accg[m][n] = __builtin_amdgcn_mfma_f32_16x16x32_bf16(af[m], bg[n], accg[m][n], 0, 0, 0);
                    accu[m][n] = __builtin_amdgcn_mfma_f32_16x16x32_bf16(af[m], bu[n], accu[m][n], 0, 0, 0);
                }
        }
        __syncthreads();   // reads done before next overwrite
    }

    // epilogue: h = silu(gate) * up
#pragma unroll
    for (int m = 0; m < 4; ++m)
#pragma unroll
        for (int n = 0; n < 2; ++n)
#pragma unroll
            for (int r = 0; r < 4; ++r) {
                int rloc = wm * 64 + m * 16 + (lane >> 4) * 4 + r;
                if (rloc < mlen) {
                    int col = wn * 32 + n * 16 + lr;
                    float g = accg[m][n][r], u = accu[m][n][r];
                    float h = (g / (1.f + __expf(-g))) * u;
                    H[(size_t)(m0 + rloc) * DFF_DIM + n0 + col] = f2bf(h);
                }
            }
}

// ---------------- GEMM2 fast: H @ w2b_e^T, scale, atomicAdd ------------------
__global__ __launch_bounds__(256, 3)
void gemm2p_kernel(const u16* __restrict__ H, const u16* __restrict__ w2b,
                   const int* __restrict__ sched, const int* __restrict__ row_token,
                   const float* __restrict__ row_w, float* __restrict__ out) {
    __shared__ u16 lA[BM * BK];
    __shared__ u16 lB[BM * BK];

    DECODE_BLOCK();
    const int n0 = n0i * 128;

    const int tid  = threadIdx.x;
    const int lane = tid & 63;
    const int wave = tid >> 6;
    const int wm = wave >> 1, wn = wave & 1;
    const int lr = lane & 15, lk = lane >> 4;

    const u16* asrc[4];
    const u16* bsrc[4];
    int aoff[4];
#pragma unroll
    for (int i = 0; i < 4; ++i) {
        int R = i * 32 + wave * 8 + (lane >> 3);
        int grow = m0 + R; if (grow > NROWS - 1) grow = NROWS - 1;
        int c8 = ((lane & 7) ^ (R & 7)) * 8;
        asrc[i] = H + (size_t)grow * DFF_DIM + c8;
        bsrc[i] = w2b + ((size_t)e * D_DIM + (n0 + R)) * DFF_DIM + c8;
        aoff[i] = i * 2048 + wave * 512;
    }

    f32x4 acc[4][4];
#pragma unroll
    for (int m = 0; m < 4; ++m)
#pragma unroll
        for (int n = 0; n < 4; ++n) acc[m][n] = (f32x4){0.f, 0.f, 0.f, 0.f};

    const int KT = DFF_DIM / BK;   // 16
    for (int kt = 0; kt < KT; ++kt) {
        GLL8(kt * BK);
        __syncthreads();
#pragma unroll
        for (int ks = 0; ks < 2; ++ks) {
            const int inner = ks * 64 + lk * 16;
            bf16x8 af[4], bfr[4];
#pragma unroll
            for (int m = 0; m < 4; ++m)
                af[m] = lds_read8_swz(lA, wm * 64 + m * 16 + lr, inner);
#pragma unroll
            for (int n = 0; n < 4; ++n)
                bfr[n] = lds_read8_swz(lB, wn * 64 + n * 16 + lr, inner);
#pragma unroll
            for (int m = 0; m < 4; ++m)
#pragma unroll
                for (int n = 0; n < 4; ++n)
                    acc[m][n] = __builtin_amdgcn_mfma_f32_16x16x32_bf16(af[m], bfr[n], acc[m][n], 0, 0, 0);
        }
        __syncthreads();
    }

#pragma unroll
    for (int m = 0; m < 4; ++m)
#pragma unroll
        for (int n = 0; n < 4; ++n)
#pragma unroll
            for (int r = 0; r < 4; ++r) {
                int rloc = wm * 64 + m * 16 + (lane >> 4) * 4 + r;
                if (rloc < mlen) {
                    int grow = m0 + rloc;
                    int tok  = row_token[grow];
                    float w  = row_w[grow];
                    int col  = wn * 64 + n * 16 + lr;
                    atomicAdd(&out[(size_t)tok * D_DIM + n0 + col], acc[m][n][r] * w);
                }
            }
}

// ======================= fallback path (ws too small) ========================
__global__ void cvt_x_kernel(const float* __restrict__ X, u16* __restrict__ Xb,
                             float* __restrict__ out) {
    int idx = (blockIdx.x * 256 + threadIdx.x) * 8;
    cvt8(X + idx, Xb + idx);
    f32x4 z = (f32x4){0.f, 0.f, 0.f, 0.f};
    *(f32x4*)(out + idx) = z;
    *(f32x4*)(out + idx + 4) = z;
}

__global__ void route_kernel(const int* __restrict__ topk_ids,
                             const float* __restrict__ topk_w,
                             int* __restrict__ sched,
                             int* __restrict__ row_token,
                             float* __restrict__ row_w) {
    __shared__ int cnt[NEXP], off[NEXP], cur[NEXP];
    route_body(topk_ids, topk_w, sched, row_token, row_w, cnt, off, cur);
}

#define GLL_A(k0, dst)                                                    \
    _Pragma("unroll") for (int i = 0; i < 4; ++i)                         \
        gll16(asrc[i] + (k0), &(dst)[aoff[i]]);

#define LOAD_RB(rb, k0)                                                   \
    _Pragma("unroll") for (int i = 0; i < 4; ++i) {                       \
        rb[i][0] = *(const f32x4*)(bptr[i] + (k0));                       \
        rb[i][1] = *(const f32x4*)(bptr[i] + (k0) + 4);                   \
    }

#define CVT_WRITE(rb, dst)                                                \
    _Pragma("unroll") for (int i = 0; i < 4; ++i) {                       \
        bf16x8 vb;                                                        \
        _Pragma("unroll") for (int j = 0; j < 4; ++j) {                   \
            vb[j] = (short)f2bf(rb[i][0][j]);                             \
            vb[j + 4] = (short)f2bf(rb[i][1][j]);                         \
        }                                                                 \
        *(bf16x8*)((char*)(dst) + wroff[i]) = vb;                         \
    }

__global__ __launch_bounds__(256, 3)
void gemm1f_kernel(const u16* __restrict__ Xb, const float* __restrict__ w1,
                   const int* __restrict__ sched, const int* __restrict__ row_token,
                   u16* __restrict__ H) {
    __shared__ u16 lA[2][BM * BK];
    __shared__ u16 lB[BM * BK];

    DECODE_BLOCK();
    const int n0 = n0i * 64;

    const int tid  = threadIdx.x;
    const int lane = tid & 63;
    const int wave = tid >> 6;
    const int wm = wave >> 1, wn = wave & 1;
    const int lr = lane & 15, lk = lane >> 4;

    const u16* asrc[4];
    int aoff[4];
#pragma unroll
    for (int i = 0; i < 4; ++i) {
        int R = i * 32 + wave * 8 + (lane >> 3);
        int grow = m0 + R; if (grow > NROWS - 1) grow = NROWS - 1;
        int tok = row_token[grow];
        asrc[i] = Xb + (size_t)tok * D_DIM + (size_t)(((lane & 7) ^ (R & 7)) * 8);
        aoff[i] = i * 2048 + wave * 512;
    }
    const float* bptr[4];
    int wroff[4];
#pragma unroll
    for (int i = 0; i < 4; ++i) {
        int chunk = i * 256 + tid;
        int row = chunk >> 3, c8 = chunk & 7;
        int gcol = (row < 64) ? (n0 + row) : (DFF_DIM + n0 + (row - 64));
        bptr[i] = w1 + ((size_t)e * (2 * DFF_DIM) + gcol) * D_DIM + c8 * 8;
        wroff[i] = row * 128 + ((c8 * 16) ^ ((row & 7) << 4));
    }

    f32x4 rb[4][2];
    f32x4 accg[4][2], accu[4][2];
#pragma unroll
    for (int m = 0; m < 4; ++m)
#pragma unroll
        for (int n = 0; n < 2; ++n) {
            accg[m][n] = (f32x4){0.f, 0.f, 0.f, 0.f};
            accu[m][n] = (f32x4){0.f, 0.f, 0.f, 0.f};
        }

#define MFMA_G1(bufA, bufB)                                               \
    _Pragma("unroll") for (int ks = 0; ks < 2; ++ks) {                    \
        const int inner = ks * 64 + lk * 16;                              \
        bf16x8 af[4], bg[2], bu[2];                                       \
        _Pragma("unroll") for (int m = 0; m < 4; ++m)                     \
            af[m] = lds_read8_swz(bufA, wm * 64 + m * 16 + lr, inner);    \
        _Pragma("unroll") for (int n = 0; n < 2; ++n) {                   \
            bg[n] = lds_read8_swz(bufB, wn * 32 + n * 16 + lr, inner);    \
            bu[n] = lds_read8_swz(bufB, 64 + wn * 32 + n * 16 + lr, inner); \
        }                                                                 \
        _Pragma("unroll") for (int m = 0; m < 4; ++m)                     \
            _Pragma("unroll") for (int n = 0; n < 2; ++n) {               \
                accg[m][n] = __builtin_amdgcn_mfma_f32_16x16x32_bf16(af[m], bg[n], accg[m][n], 0, 0, 0); \
                accu[m][n] = __builtin_amdgcn_mfma_f32_16x16x32_bf16(af[m], bu[n], accu[m][n], 0, 0, 0); \
            }                                                             \
    }

    const int KT = D_DIM / BK;
    LOAD_RB(rb, 0);
    GLL_A(0, lA[0]);
    CVT_WRITE(rb, lB);
    __syncthreads();

    for (int kt = 0, cur = 0; kt < KT; ++kt, cur ^= 1) {
        if (kt + 1 < KT) {
            LOAD_RB(rb, (kt + 1) * BK);
            GLL_A((kt + 1) * BK, lA[cur ^ 1]);
        }
        PIN();
        MFMA_G1(lA[cur], lB);
        BAR_LGKM();
        if (kt + 1 < KT) { CVT_WRITE(rb, lB); }
        __syncthreads();
    }
#undef MFMA_G1

#pragma unroll
    for (int m = 0; m < 4; ++m)
#pragma unroll
        for (int n = 0; n < 2; ++n)
#pragma unroll
            for (int r = 0; r < 4; ++r) {
                int rloc = wm * 64 + m * 16 + (lane >> 4) * 4 + r;
                if (rloc < mlen) {
                    int col = wn * 32 + n * 16 + lr;
                    float g = accg[m][n][r], u = accu[m][n][r];
                    float h = (g / (1.f + __expf(-g))) * u;
                    H[(size_t)(m0 + rloc) * DFF_DIM + n0 + col] = f2bf(h);
                }
            }
}

__global__ __launch_bounds__(256, 3)
void gemm2f_kernel(const u16* __restrict__ H, const float* __restrict__ w2,
                   const int* __restrict__ sched, const int* __restrict__ row_token,
                   const float* __restrict__ row_w, float* __restrict__ out) {
    __shared__ u16 lA[2][BM * BK];
    __shared__ u16 lB[BM * BK];

    DECODE_BLOCK();
    const int n0 = n0i * 128;

    const int tid  = threadIdx.x;
    const int lane = tid & 63;
    const int wave = tid >> 6;
    const int wm = wave >> 1, wn = wave & 1;
    const int lr = lane & 15, lk = lane >> 4;

    const u16* asrc[4];
    int aoff[4];
#pragma unroll
    for (int i = 0; i < 4; ++i) {
        int R = i * 32 + wave * 8 + (lane >> 3);
        int grow = m0 + R; if (grow > NROWS - 1) grow = NROWS - 1;
        asrc[i] = H + (size_t)grow * DFF_DIM + (size_t)(((lane & 7) ^ (R & 7)) * 8);
        aoff[i] = i * 2048 + wave * 512;
    }
    const float* bptr[4];
    int wroff[4];
#pragma unroll
    for (int i = 0; i < 4; ++i) {
        int chunk = i * 256 + tid;
        int row = chunk >> 3, c8 = chunk & 7;
        bptr[i] = w2 + ((size_t)e * D_DIM + (n0 + row)) * DFF_DIM + c8 * 8;
        wroff[i] = row * 128 + ((c8 * 16) ^ ((row & 7) << 4));
    }

    f32x4 rb[4][2];
    f32x4 acc[4][4];
#pragma unroll
    for (int m = 0; m < 4; ++m)
#pragma unroll
        for (int n = 0; n < 4; ++n) acc[m][n] = (f32x4){0.f, 0.f, 0.f, 0.f};

#define MFMA_G2(bufA, bufB)                                               \
    _Pragma("unroll") for (int ks = 0; ks < 2; ++ks) {                    \
        const int inner = ks * 64 + lk * 16;                              \
        bf16x8 af[4], bfr[4];                                             \
        _Pragma("unroll") for (int m = 0; m < 4; ++m)                     \
            af[m] = lds_read8_swz(bufA, wm * 64 + m * 16 + lr, inner);    \
        _Pragma("unroll") for (int n = 0; n < 4; ++n)                     \
            bfr[n] = lds_read8_swz(bufB, wn * 64 + n * 16 + lr, inner);   \
        _Pragma("unroll") for (int m = 0; m < 4; ++m)                     \
            _Pragma("unroll") for (int n = 0; n < 4; ++n)                 \
                acc[m][n] = __builtin_amdgcn_mfma_f32_16x16x32_bf16(af[m], bfr[n], acc[m][n], 0, 0, 0); \
    }

    const int KT = DFF_DIM / BK;
    LOAD_RB(rb, 0);
    GLL_A(0, lA[0]);
    CVT_WRITE(rb, lB);
    __syncthreads();

    for (int kt = 0, cur = 0; kt < KT; ++kt, cur ^= 1) {
        if (kt + 1 < KT) {
            LOAD_RB(rb, (kt + 1) * BK);
            GLL_A((kt + 1) * BK, lA[cur ^ 1]);
        }
        PIN();
        MFMA_G2(lA[cur], lB);
        BAR_LGKM();
        if (kt + 1 < KT) { CVT_WRITE(rb, lB); }
        __syncthreads();
    }
#undef MFMA_G2

#pragma unroll
    for (int m = 0; m < 4; ++m)
#pragma unroll
        for (int n = 0; n < 4; ++n)
#pragma unroll
            for (int r = 0; r < 4; ++r) {
                int rloc = wm * 64 + m * 16 + (lane >> 4) * 4 + r;
                if (rloc < mlen) {
                    int grow = m0 + rloc;
                    int tok  = row_token[grow];
                    float w  = row_w[grow];
                    int col  = wn * 64 + n * 16 + lr;
                    atomicAdd(&out[(size_t)tok * D_DIM + n0 + col], acc[m][n][r] * w);
                }
            }
}

extern "C" void kernel_launch(void* const* d_in, const int* in_sizes, int n_in,
                              void* d_out, int out_size, void* d_ws, size_t ws_size,
                              hipStream_t stream) {
    const float* X  = (const float*)d_in[0];
    const float* w1 = (const float*)d_in[1];
    const float* w2 = (const float*)d_in[2];
    const float* tw = (const float*)d_in[3];
    const int*   ti = (const int*)d_in[4];

    int*   sched     = (int*)d_ws;
    int*   row_token = (int*)((char*)d_ws + 512);
    float* row_w     = (float*)((char*)d_ws + 512 + 4 * NROWS);
    u16*   Xb        = (u16*)((char*)d_ws + XB_OFF);
    u16*   H         = (u16*)((char*)d_ws + H_OFF);

    if (ws_size >= WS_NEED) {
        u16* w1b = (u16*)((char*)d_ws + W1B_OFF);
        u16* w2b = (u16*)((char*)d_ws + W2B_OFF);
        prep_kernel<<<PREP_GRID, 256, 0, stream>>>(w1, w2, X, w1b, w2b, Xb,
                                                   (float*)d_out, ti, tw,
                                                   sched, row_token, row_w);
        gemm1p_kernel<<<GRID_G, 256, 0, stream>>>(Xb, w1b, sched, row_token, H);
        gemm2p_kernel<<<GRID_G, 256, 0, stream>>>(H, w2b, sched, row_token, row_w, (float*)d_out);
    } else {
        route_kernel<<<1, 256, 0, stream>>>(ti, tw, sched, row_token, row_w);
        cvt_x_kernel<<<(T_TOK * D_DIM) / (256 * 8), 256, 0, stream>>>(X, Xb, (float*)d_out);
        gemm1f_kernel<<<GRID_G, 256, 0, stream>>>(Xb, w1, sched, row_token, H);
        gemm2f_kernel<<<GRID_G, 256, 0, stream>>>(H, w2, sched, row_token, row_w, (float*)d_out);
    }
}

// Round 11
// 166.667 us; speedup vs baseline: 1.0677x; 1.0677x over previous
//
#include <hip/hip_runtime.h>
#include <hip/hip_bf16.h>
#include <stdint.h>

typedef __attribute__((ext_vector_type(4))) float f32x4;
typedef __attribute__((ext_vector_type(8))) short bf16x8;
typedef unsigned short u16;

#define T_TOK   2048
#define D_DIM   2048
#define DFF_DIM 1024
#define NEXP    8
#define TOPK    2
#define NROWS   (T_TOK * TOPK)   // 4096
#define BM      128
#define BK      64
#define MAX_MB  40
#define GRID_G  (16 * MAX_MB)    // 640 = 8 XCDs x 80

// ---- workspace layout ----
#define XB_OFF    65536
#define XB_BYTES  ((size_t)T_TOK * D_DIM * 2)                  // 8 MB
#define H_OFF     (XB_OFF + XB_BYTES)
#define H_BYTES   ((size_t)NROWS * DFF_DIM * 2)                // 8 MB
#define W1B_OFF   (H_OFF + H_BYTES)
#define W1B_BYTES ((size_t)NEXP * 2 * DFF_DIM * D_DIM * 2)     // 64 MB
#define W2B_OFF   (W1B_OFF + W1B_BYTES)
#define W2B_BYTES ((size_t)NEXP * D_DIM * DFF_DIM * 2)         // 32 MB
#define WS_NEED   (W2B_OFF + W2B_BYTES)                        // ~112 MB

// prep segmentation (chunks of 8 f32)
#define W1_T   ((size_t)NEXP * 2 * DFF_DIM * D_DIM / 8)  // 2^22
#define W2_T   ((size_t)NEXP * D_DIM * DFF_DIM / 8)      // 2^21
#define X_T    ((size_t)T_TOK * D_DIM / 8)               // 2^19
#define PREP_CHUNKS (W1_T + W2_T + X_T)                  // 6,815,744
#define PREP_BLKS 2048

#define PIN() asm volatile("" ::: "memory")
#define BAR_LGKM()                                                        \
    asm volatile("s_waitcnt lgkmcnt(0)" ::: "memory");                    \
    __builtin_amdgcn_s_barrier()

__device__ __forceinline__ u16 f2bf(float f) {
    __hip_bfloat16 h = __float2bfloat16(f);
    return *reinterpret_cast<u16*>(&h);
}

// normal-cache conversion (fallback path)
__device__ __forceinline__ void cvt8(const float* src, u16* dst) {
    f32x4 a = *(const f32x4*)src;
    f32x4 b = *(const f32x4*)(src + 4);
    bf16x8 v;
#pragma unroll
    for (int j = 0; j < 4; ++j) { v[j] = (short)f2bf(a[j]); v[j + 4] = (short)f2bf(b[j]); }
    *(bf16x8*)dst = v;
}

// nontemporal-source conversion: f32 input is dead after this read -> bypass
// L2/L3 allocation so the bf16 outputs (reused by the GEMMs) stay resident.
__device__ __forceinline__ void cvt8_nt(const float* src, u16* dst) {
    f32x4 a = __builtin_nontemporal_load((const f32x4*)src);
    f32x4 b = __builtin_nontemporal_load(((const f32x4*)src) + 1);
    bf16x8 v;
#pragma unroll
    for (int j = 0; j < 4; ++j) { v[j] = (short)f2bf(a[j]); v[j + 4] = (short)f2bf(b[j]); }
    *(bf16x8*)dst = v;
}

__device__ __forceinline__ void gll16(const u16* gsrc, const u16* lds) {
    __builtin_amdgcn_global_load_lds(
        (const __attribute__((address_space(1))) uint32_t*)gsrc,
        (__attribute__((address_space(3))) uint32_t*)lds, 16, 0, 0);
}

// tile [128 rows][64 bf16=128B]; content XOR-swizzled by row
__device__ __forceinline__ bf16x8 lds_read8_swz(const u16* base, int row, int inner) {
    int off = row * 128 + (inner ^ ((row & 7) << 4));
    return *(const bf16x8*)((const char*)base + off);
}

__device__ __forceinline__ void route_body(const int* topk_ids, const float* topk_w,
                                           int* sched, int* row_token, float* row_w,
                                           int* cnt, int* off, int* cur) {
    const int tid = threadIdx.x;
    if (tid < NEXP) cnt[tid] = 0;
    __syncthreads();
    for (int p = tid; p < NROWS; p += blockDim.x)
        atomicAdd(&cnt[topk_ids[p]], 1);
    __syncthreads();
    if (tid == 0) {
        int acc = 0, mb = 0;
        for (int e = 0; e < NEXP; ++e) {
            off[e] = acc;
            int c = cnt[e];
            for (int m0 = 0; m0 < c; m0 += BM) {
                sched[1 + 3 * mb] = e;
                sched[2 + 3 * mb] = acc + m0;
                sched[3 + 3 * mb] = (c - m0 < BM) ? (c - m0) : BM;
                ++mb;
            }
            acc += c;
        }
        sched[0] = mb;
    }
    if (tid < NEXP) cur[tid] = 0;
    __syncthreads();
    for (int p = tid; p < NROWS; p += blockDim.x) {
        int e = topk_ids[p];
        int slot = off[e] + atomicAdd(&cur[e], 1);
        row_token[slot] = p / TOPK;
        row_w[slot]     = topk_w[p];
    }
}

// ---------------- prepass: grid-stride, nontemporal f32 reads ----------------
__global__ void prep_kernel(const float* __restrict__ w1, const float* __restrict__ w2,
                            const float* __restrict__ X,
                            u16* __restrict__ w1b, u16* __restrict__ w2b,
                            u16* __restrict__ Xb, float* __restrict__ out,
                            const int* __restrict__ topk_ids,
                            const float* __restrict__ topk_w,
                            int* __restrict__ sched, int* __restrict__ row_token,
                            float* __restrict__ row_w) {
    __shared__ int cnt[NEXP], off[NEXP], cur[NEXP];
    if (blockIdx.x == PREP_BLKS) {   // routing-only block
        route_body(topk_ids, topk_w, sched, row_token, row_w, cnt, off, cur);
        return;
    }
    const size_t stride = (size_t)PREP_BLKS * 256;
    for (size_t t = (size_t)blockIdx.x * 256 + threadIdx.x; t < PREP_CHUNKS; t += stride) {
        if (t < W1_T) {
            cvt8_nt(w1 + t * 8, w1b + t * 8);
        } else if (t < W1_T + W2_T) {
            size_t u = t - W1_T;
            cvt8_nt(w2 + u * 8, w2b + u * 8);
        } else {
            size_t u = t - (W1_T + W2_T);
            cvt8_nt(X + u * 8, Xb + u * 8);
            f32x4 z = (f32x4){0.f, 0.f, 0.f, 0.f};
            *(f32x4*)(out + u * 8) = z;
            *(f32x4*)(out + u * 8 + 4) = z;
        }
    }
}

// XCD map: blocks sharing a B-tile (same e,n0; different m0) land on ONE XCD.
#define DECODE_BLOCK()                                                    \
    const int bid   = blockIdx.x;                                         \
    const int xcd   = bid & 7;                                            \
    const int local = bid >> 3;            /* 0..79 */                    \
    const int n0h   = local / MAX_MB;      /* 0..1  */                    \
    const int mb    = local - n0h * MAX_MB;                               \
    const int n0i   = xcd * 2 + n0h;       /* 0..15 */                    \
    if (mb >= sched[0]) return;                                           \
    const int e    = sched[1 + 3 * mb];                                   \
    const int m0   = sched[2 + 3 * mb];                                   \
    const int mlen = sched[3 + 3 * mb]

#define GLL8(k0)                                                          \
    _Pragma("unroll") for (int i = 0; i < 4; ++i)                         \
        gll16(asrc[i] + (k0), &lA[aoff[i]]);                              \
    _Pragma("unroll") for (int i = 0; i < 4; ++i)                         \
        gll16(bsrc[i] + (k0), &lB[aoff[i]]);

// ---------------- GEMM1 fast: gathered Xb @ w1b_e^T, silu*up -> H ------------
__global__ __launch_bounds__(256, 3)
void gemm1p_kernel(const u16* __restrict__ Xb, const u16* __restrict__ w1b,
                   const int* __restrict__ sched, const int* __restrict__ row_token,
                   u16* __restrict__ H) {
    __shared__ u16 lA[BM * BK];   // 16KB, gll (linear dest, pre-swz src)
    __shared__ u16 lB[BM * BK];   // 16KB, gll

    DECODE_BLOCK();
    const int n0 = n0i * 64;

    const int tid  = threadIdx.x;
    const int lane = tid & 63;
    const int wave = tid >> 6;
    const int wm = wave >> 1, wn = wave & 1;
    const int lr = lane & 15, lk = lane >> 4;

    const u16* asrc[4];
    const u16* bsrc[4];
    int aoff[4];
#pragma unroll
    for (int i = 0; i < 4; ++i) {
        int R = i * 32 + wave * 8 + (lane >> 3);
        int grow = m0 + R; if (grow > NROWS - 1) grow = NROWS - 1;
        int tok = row_token[grow];
        int c8 = ((lane & 7) ^ (R & 7)) * 8;
        asrc[i] = Xb + (size_t)tok * D_DIM + c8;
        int gr = (R < 64) ? (n0 + R) : (DFF_DIM + n0 + (R - 64));
        bsrc[i] = w1b + ((size_t)e * (2 * DFF_DIM) + gr) * D_DIM + c8;
        aoff[i] = i * 2048 + wave * 512;
    }

    f32x4 accg[4][2], accu[4][2];
#pragma unroll
    for (int m = 0; m < 4; ++m)
#pragma unroll
        for (int n = 0; n < 2; ++n) {
            accg[m][n] = (f32x4){0.f, 0.f, 0.f, 0.f};
            accu[m][n] = (f32x4){0.f, 0.f, 0.f, 0.f};
        }

    const int KT = D_DIM / BK;   // 32
    for (int kt = 0; kt < KT; ++kt) {
        GLL8(kt * BK);
        __syncthreads();   // drains glls (vmcnt 0)
#pragma unroll
        for (int ks = 0; ks < 2; ++ks) {
            const int inner = ks * 64 + lk * 16;
            bf16x8 af[4], bg[2], bu[2];
#pragma unroll
            for (int m = 0; m < 4; ++m)
                af[m] = lds_read8_swz(lA, wm * 64 + m * 16 + lr, inner);
#pragma unroll
            for (int n = 0; n < 2; ++n) {
                bg[n] = lds_read8_swz(lB, wn * 32 + n * 16 + lr, inner);
                bu[n] = lds_read8_swz(lB, 64 + wn * 32 + n * 16 + lr, inner);
            }
#pragma unroll
            for (int m = 0; m < 4; ++m)
#pragma unroll
                for (int n = 0; n < 2; ++n) {
                    accg[m][n] = __builtin_amdgcn_mfma_f32_16x16x32_bf16(af[m], bg[n], accg[m][n], 0, 0, 0);
                    accu[m][n] = __builtin_amdgcn_mfma_f32_16x16x32_bf16(af[m], bu[n], accu[m][n], 0, 0, 0);
                }
        }
        __syncthreads();   // reads done before next overwrite
    }

    // epilogue: h = silu(gate) * up
#pragma unroll
    for (int m = 0; m < 4; ++m)
#pragma unroll
        for (int n = 0; n < 2; ++n)
#pragma unroll
            for (int r = 0; r < 4; ++r) {
                int rloc = wm * 64 + m * 16 + (lane >> 4) * 4 + r;
                if (rloc < mlen) {
                    int col = wn * 32 + n * 16 + lr;
                    float g = accg[m][n][r], u = accu[m][n][r];
                    float h = (g / (1.f + __expf(-g))) * u;
                    H[(size_t)(m0 + rloc) * DFF_DIM + n0 + col] = f2bf(h);
                }
            }
}

// ---------------- GEMM2 fast: H @ w2b_e^T, scale, atomicAdd ------------------
__global__ __launch_bounds__(256, 3)
void gemm2p_kernel(const u16* __restrict__ H, const u16* __restrict__ w2b,
                   const int* __restrict__ sched, const int* __restrict__ row_token,
                   const float* __restrict__ row_w, float* __restrict__ out) {
    __shared__ u16 lA[BM * BK];
    __shared__ u16 lB[BM * BK];

    DECODE_BLOCK();
    const int n0 = n0i * 128;

    const int tid  = threadIdx.x;
    const int lane = tid & 63;
    const int wave = tid >> 6;
    const int wm = wave >> 1, wn = wave & 1;
    const int lr = lane & 15, lk = lane >> 4;

    const u16* asrc[4];
    const u16* bsrc[4];
    int aoff[4];
#pragma unroll
    for (int i = 0; i < 4; ++i) {
        int R = i * 32 + wave * 8 + (lane >> 3);
        int grow = m0 + R; if (grow > NROWS - 1) grow = NROWS - 1;
        int c8 = ((lane & 7) ^ (R & 7)) * 8;
        asrc[i] = H + (size_t)grow * DFF_DIM + c8;
        bsrc[i] = w2b + ((size_t)e * D_DIM + (n0 + R)) * DFF_DIM + c8;
        aoff[i] = i * 2048 + wave * 512;
    }

    f32x4 acc[4][4];
#pragma unroll
    for (int m = 0; m < 4; ++m)
#pragma unroll
        for (int n = 0; n < 4; ++n) acc[m][n] = (f32x4){0.f, 0.f, 0.f, 0.f};

    const int KT = DFF_DIM / BK;   // 16
    for (int kt = 0; kt < KT; ++kt) {
        GLL8(kt * BK);
        __syncthreads();
#pragma unroll
        for (int ks = 0; ks < 2; ++ks) {
            const int inner = ks * 64 + lk * 16;
            bf16x8 af[4], bfr[4];
#pragma unroll
            for (int m = 0; m < 4; ++m)
                af[m] = lds_read8_swz(lA, wm * 64 + m * 16 + lr, inner);
#pragma unroll
            for (int n = 0; n < 4; ++n)
                bfr[n] = lds_read8_swz(lB, wn * 64 + n * 16 + lr, inner);
#pragma unroll
            for (int m = 0; m < 4; ++m)
#pragma unroll
                for (int n = 0; n < 4; ++n)
                    acc[m][n] = __builtin_amdgcn_mfma_f32_16x16x32_bf16(af[m], bfr[n], acc[m][n], 0, 0, 0);
        }
        __syncthreads();
    }

#pragma unroll
    for (int m = 0; m < 4; ++m)
#pragma unroll
        for (int n = 0; n < 4; ++n)
#pragma unroll
            for (int r = 0; r < 4; ++r) {
                int rloc = wm * 64 + m * 16 + (lane >> 4) * 4 + r;
                if (rloc < mlen) {
                    int grow = m0 + rloc;
                    int tok  = row_token[grow];
                    float w  = row_w[grow];
                    int col  = wn * 64 + n * 16 + lr;
                    atomicAdd(&out[(size_t)tok * D_DIM + n0 + col], acc[m][n][r] * w);
                }
            }
}

// ======================= fallback path (ws too small) ========================
__global__ void cvt_x_kernel(const float* __restrict__ X, u16* __restrict__ Xb,
                             float* __restrict__ out) {
    int idx = (blockIdx.x * 256 + threadIdx.x) * 8;
    cvt8(X + idx, Xb + idx);
    f32x4 z = (f32x4){0.f, 0.f, 0.f, 0.f};
    *(f32x4*)(out + idx) = z;
    *(f32x4*)(out + idx + 4) = z;
}

__global__ void route_kernel(const int* __restrict__ topk_ids,
                             const float* __restrict__ topk_w,
                             int* __restrict__ sched,
                             int* __restrict__ row_token,
                             float* __restrict__ row_w) {
    __shared__ int cnt[NEXP], off[NEXP], cur[NEXP];
    route_body(topk_ids, topk_w, sched, row_token, row_w, cnt, off, cur);
}

#define GLL_A(k0, dst)                                                    \
    _Pragma("unroll") for (int i = 0; i < 4; ++i)                         \
        gll16(asrc[i] + (k0), &(dst)[aoff[i]]);

#define LOAD_RB(rb, k0)                                                   \
    _Pragma("unroll") for (int i = 0; i < 4; ++i) {                       \
        rb[i][0] = *(const f32x4*)(bptr[i] + (k0));                       \
        rb[i][1] = *(const f32x4*)(bptr[i] + (k0) + 4);                   \
    }

#define CVT_WRITE(rb, dst)                                                \
    _Pragma("unroll") for (int i = 0; i < 4; ++i) {                       \
        bf16x8 vb;                                                        \
        _Pragma("unroll") for (int j = 0; j < 4; ++j) {                   \
            vb[j] = (short)f2bf(rb[i][0][j]);                             \
            vb[j + 4] = (short)f2bf(rb[i][1][j]);                         \
        }                                                                 \
        *(bf16x8*)((char*)(dst) + wroff[i]) = vb;                         \
    }

__global__ __launch_bounds__(256, 3)
void gemm1f_kernel(const u16* __restrict__ Xb, const float* __restrict__ w1,
                   const int* __restrict__ sched, const int* __restrict__ row_token,
                   u16* __restrict__ H) {
    __shared__ u16 lA[2][BM * BK];
    __shared__ u16 lB[BM * BK];

    DECODE_BLOCK();
    const int n0 = n0i * 64;

    const int tid  = threadIdx.x;
    const int lane = tid & 63;
    const int wave = tid >> 6;
    const int wm = wave >> 1, wn = wave & 1;
    const int lr = lane & 15, lk = lane >> 4;

    const u16* asrc[4];
    int aoff[4];
#pragma unroll
    for (int i = 0; i < 4; ++i) {
        int R = i * 32 + wave * 8 + (lane >> 3);
        int grow = m0 + R; if (grow > NROWS - 1) grow = NROWS - 1;
        int tok = row_token[grow];
        asrc[i] = Xb + (size_t)tok * D_DIM + (size_t)(((lane & 7) ^ (R & 7)) * 8);
        aoff[i] = i * 2048 + wave * 512;
    }
    const float* bptr[4];
    int wroff[4];
#pragma unroll
    for (int i = 0; i < 4; ++i) {
        int chunk = i * 256 + tid;
        int row = chunk >> 3, c8 = chunk & 7;
        int gcol = (row < 64) ? (n0 + row) : (DFF_DIM + n0 + (row - 64));
        bptr[i] = w1 + ((size_t)e * (2 * DFF_DIM) + gcol) * D_DIM + c8 * 8;
        wroff[i] = row * 128 + ((c8 * 16) ^ ((row & 7) << 4));
    }

    f32x4 rb[4][2];
    f32x4 accg[4][2], accu[4][2];
#pragma unroll
    for (int m = 0; m < 4; ++m)
#pragma unroll
        for (int n = 0; n < 2; ++n) {
            accg[m][n] = (f32x4){0.f, 0.f, 0.f, 0.f};
            accu[m][n] = (f32x4){0.f, 0.f, 0.f, 0.f};
        }

#define MFMA_G1(bufA, bufB)                                               \
    _Pragma("unroll") for (int ks = 0; ks < 2; ++ks) {                    \
        const int inner = ks * 64 + lk * 16;                              \
        bf16x8 af[4], bg[2], bu[2];                                       \
        _Pragma("unroll") for (int m = 0; m < 4; ++m)                     \
            af[m] = lds_read8_swz(bufA, wm * 64 + m * 16 + lr, inner);    \
        _Pragma("unroll") for (int n = 0; n < 2; ++n) {                   \
            bg[n] = lds_read8_swz(bufB, wn * 32 + n * 16 + lr, inner);    \
            bu[n] = lds_read8_swz(bufB, 64 + wn * 32 + n * 16 + lr, inner); \
        }                                                                 \
        _Pragma("unroll") for (int m = 0; m < 4; ++m)                     \
            _Pragma("unroll") for (int n = 0; n < 2; ++n) {               \
                accg[m][n] = __builtin_amdgcn_mfma_f32_16x16x32_bf16(af[m], bg[n], accg[m][n], 0, 0, 0); \
                accu[m][n] = __builtin_amdgcn_mfma_f32_16x16x32_bf16(af[m], bu[n], accu[m][n], 0, 0, 0); \
            }                                                             \
    }

    const int KT = D_DIM / BK;
    LOAD_RB(rb, 0);
    GLL_A(0, lA[0]);
    CVT_WRITE(rb, lB);
    __syncthreads();

    for (int kt = 0, cur = 0; kt < KT; ++kt, cur ^= 1) {
        if (kt + 1 < KT) {
            LOAD_RB(rb, (kt + 1) * BK);
            GLL_A((kt + 1) * BK, lA[cur ^ 1]);
        }
        PIN();
        MFMA_G1(lA[cur], lB);
        BAR_LGKM();
        if (kt + 1 < KT) { CVT_WRITE(rb, lB); }
        __syncthreads();
    }
#undef MFMA_G1

#pragma unroll
    for (int m = 0; m < 4; ++m)
#pragma unroll
        for (int n = 0; n < 2; ++n)
#pragma unroll
            for (int r = 0; r < 4; ++r) {
                int rloc = wm * 64 + m * 16 + (lane >> 4) * 4 + r;
                if (rloc < mlen) {
                    int col = wn * 32 + n * 16 + lr;
                    float g = accg[m][n][r], u = accu[m][n][r];
                    float h = (g / (1.f + __expf(-g))) * u;
                    H[(size_t)(m0 + rloc) * DFF_DIM + n0 + col] = f2bf(h);
                }
            }
}

__global__ __launch_bounds__(256, 3)
void gemm2f_kernel(const u16* __restrict__ H, const float* __restrict__ w2,
                   const int* __restrict__ sched, const int* __restrict__ row_token,
                   const float* __restrict__ row_w, float* __restrict__ out) {
    __shared__ u16 lA[2][BM * BK];
    __shared__ u16 lB[BM * BK];

    DECODE_BLOCK();
    const int n0 = n0i * 128;

    const int tid  = threadIdx.x;
    const int lane = tid & 63;
    const int wave = tid >> 6;
    const int wm = wave >> 1, wn = wave & 1;
    const int lr = lane & 15, lk = lane >> 4;

    const u16* asrc[4];
    int aoff[4];
#pragma unroll
    for (int i = 0; i < 4; ++i) {
        int R = i * 32 + wave * 8 + (lane >> 3);
        int grow = m0 + R; if (grow > NROWS - 1) grow = NROWS - 1;
        asrc[i] = H + (size_t)grow * DFF_DIM + (size_t)(((lane & 7) ^ (R & 7)) * 8);
        aoff[i] = i * 2048 + wave * 512;
    }
    const float* bptr[4];
    int wroff[4];
#pragma unroll
    for (int i = 0; i < 4; ++i) {
        int chunk = i * 256 + tid;
        int row = chunk >> 3, c8 = chunk & 7;
        bptr[i] = w2 + ((size_t)e * D_DIM + (n0 + row)) * DFF_DIM + c8 * 8;
        wroff[i] = row * 128 + ((c8 * 16) ^ ((row & 7) << 4));
    }

    f32x4 rb[4][2];
    f32x4 acc[4][4];
#pragma unroll
    for (int m = 0; m < 4; ++m)
#pragma unroll
        for (int n = 0; n < 4; ++n) acc[m][n] = (f32x4){0.f, 0.f, 0.f, 0.f};

#define MFMA_G2(bufA, bufB)                                               \
    _Pragma("unroll") for (int ks = 0; ks < 2; ++ks) {                    \
        const int inner = ks * 64 + lk * 16;                              \
        bf16x8 af[4], bfr[4];                                             \
        _Pragma("unroll") for (int m = 0; m < 4; ++m)                     \
            af[m] = lds_read8_swz(bufA, wm * 64 + m * 16 + lr, inner);    \
        _Pragma("unroll") for (int n = 0; n < 4; ++n)                     \
            bfr[n] = lds_read8_swz(bufB, wn * 64 + n * 16 + lr, inner);   \
        _Pragma("unroll") for (int m = 0; m < 4; ++m)                     \
            _Pragma("unroll") for (int n = 0; n < 4; ++n)                 \
                acc[m][n] = __builtin_amdgcn_mfma_f32_16x16x32_bf16(af[m], bfr[n], acc[m][n], 0, 0, 0); \
    }

    const int KT = DFF_DIM / BK;
    LOAD_RB(rb, 0);
    GLL_A(0, lA[0]);
    CVT_WRITE(rb, lB);
    __syncthreads();

    for (int kt = 0, cur = 0; kt < KT; ++kt, cur ^= 1) {
        if (kt + 1 < KT) {
            LOAD_RB(rb, (kt + 1) * BK);
            GLL_A((kt + 1) * BK, lA[cur ^ 1]);
        }
        PIN();
        MFMA_G2(lA[cur], lB);
        BAR_LGKM();
        if (kt + 1 < KT) { CVT_WRITE(rb, lB); }
        __syncthreads();
    }
#undef MFMA_G2

#pragma unroll
    for (int m = 0; m < 4; ++m)
#pragma unroll
        for (int n = 0; n < 4; ++n)
#pragma unroll
            for (int r = 0; r < 4; ++r) {
                int rloc = wm * 64 + m * 16 + (lane >> 4) * 4 + r;
                if (rloc < mlen) {
                    int grow = m0 + rloc;
                    int tok  = row_token[grow];
                    float w  = row_w[grow];
                    int col  = wn * 64 + n * 16 + lr;
                    atomicAdd(&out[(size_t)tok * D_DIM + n0 + col], acc[m][n][r] * w);
                }
            }
}

extern "C" void kernel_launch(void* const* d_in, const int* in_sizes, int n_in,
                              void* d_out, int out_size, void* d_ws, size_t ws_size,
                              hipStream_t stream) {
    const float* X  = (const float*)d_in[0];
    const float* w1 = (const float*)d_in[1];
    const float* w2 = (const float*)d_in[2];
    const float* tw = (const float*)d_in[3];
    const int*   ti = (const int*)d_in[4];

    int*   sched     = (int*)d_ws;
    int*   row_token = (int*)((char*)d_ws + 512);
    float* row_w     = (float*)((char*)d_ws + 512 + 4 * NROWS);
    u16*   Xb        = (u16*)((char*)d_ws + XB_OFF);
    u16*   H         = (u16*)((char*)d_ws + H_OFF);

    if (ws_size >= WS_NEED) {
        u16* w1b = (u16*)((char*)d_ws + W1B_OFF);
        u16* w2b = (u16*)((char*)d_ws + W2B_OFF);
        prep_kernel<<<PREP_BLKS + 1, 256, 0, stream>>>(w1, w2, X, w1b, w2b, Xb,
                                                       (float*)d_out, ti, tw,
                                                       sched, row_token, row_w);
        gemm1p_kernel<<<GRID_G, 256, 0, stream>>>(Xb, w1b, sched, row_token, H);
        gemm2p_kernel<<<GRID_G, 256, 0, stream>>>(H, w2b, sched, row_token, row_w, (float*)d_out);
    } else {
        route_kernel<<<1, 256, 0, stream>>>(ti, tw, sched, row_token, row_w);
        cvt_x_kernel<<<(T_TOK * D_DIM) / (256 * 8), 256, 0, stream>>>(X, Xb, (float*)d_out);
        gemm1f_kernel<<<GRID_G, 256, 0, stream>>>(Xb, w1, sched, row_token, H);
        gemm2f_kernel<<<GRID_G, 256, 0, stream>>>(H, w2, sched, row_token, row_w, (float*)d_out);
    }
}

// Round 12
// 164.137 us; speedup vs baseline: 1.0842x; 1.0154x over previous
//
#include <hip/hip_runtime.h>
#include <hip/hip_bf16.h>
#include <stdint.h>

typedef __attribute__((ext_vector_type(4))) float f32x4;
typedef __attribute__((ext_vector_type(8))) short bf16x8;
typedef unsigned short u16;

#define T_TOK   2048
#define D_DIM   2048
#define DFF_DIM 1024
#define NEXP    8
#define TOPK    2
#define NROWS   (T_TOK * TOPK)   // 4096
#define BM      128
#define BK      64
#define MAX_MB  40
#define GRID_G  (16 * MAX_MB)    // 640 = 8 XCDs x 80
#define CVT2_BLKS 256            // w2-conversion worker blocks appended to gemm1p

// ---- workspace layout ----
#define XB_OFF    65536
#define XB_BYTES  ((size_t)T_TOK * D_DIM * 2)                  // 8 MB
#define H_OFF     (XB_OFF + XB_BYTES)
#define H_BYTES   ((size_t)NROWS * DFF_DIM * 2)                // 8 MB
#define W1B_OFF   (H_OFF + H_BYTES)
#define W1B_BYTES ((size_t)NEXP * 2 * DFF_DIM * D_DIM * 2)     // 64 MB
#define W2B_OFF   (W1B_OFF + W1B_BYTES)
#define W2B_BYTES ((size_t)NEXP * D_DIM * DFF_DIM * 2)         // 32 MB
#define WS_NEED   (W2B_OFF + W2B_BYTES)                        // ~112 MB

// prep segmentation (chunks of 8 f32)
#define W1_T   ((size_t)NEXP * 2 * DFF_DIM * D_DIM / 8)  // 2^22
#define W2_T   ((size_t)NEXP * D_DIM * DFF_DIM / 8)      // 2^21
#define X_T    ((size_t)T_TOK * D_DIM / 8)               // 2^19
#define PREP_CHUNKS_A (W1_T + X_T)                       // w1 + X only
#define PREP_BLKS 2048

#define PIN() asm volatile("" ::: "memory")
#define BAR_LGKM()                                                        \
    asm volatile("s_waitcnt lgkmcnt(0)" ::: "memory");                    \
    __builtin_amdgcn_s_barrier()

__device__ __forceinline__ u16 f2bf(float f) {
    __hip_bfloat16 h = __float2bfloat16(f);
    return *reinterpret_cast<u16*>(&h);
}

// normal-cache conversion (fallback path)
__device__ __forceinline__ void cvt8(const float* src, u16* dst) {
    f32x4 a = *(const f32x4*)src;
    f32x4 b = *(const f32x4*)(src + 4);
    bf16x8 v;
#pragma unroll
    for (int j = 0; j < 4; ++j) { v[j] = (short)f2bf(a[j]); v[j + 4] = (short)f2bf(b[j]); }
    *(bf16x8*)dst = v;
}

// nontemporal-source conversion: f32 input is dead after this read -> bypass
// allocation so bf16 outputs (reused by the GEMMs) stay cache-resident.
__device__ __forceinline__ void cvt8_nt(const float* src, u16* dst) {
    f32x4 a = __builtin_nontemporal_load((const f32x4*)src);
    f32x4 b = __builtin_nontemporal_load(((const f32x4*)src) + 1);
    bf16x8 v;
#pragma unroll
    for (int j = 0; j < 4; ++j) { v[j] = (short)f2bf(a[j]); v[j + 4] = (short)f2bf(b[j]); }
    *(bf16x8*)dst = v;
}

__device__ __forceinline__ void gll16(const u16* gsrc, const u16* lds) {
    __builtin_amdgcn_global_load_lds(
        (const __attribute__((address_space(1))) uint32_t*)gsrc,
        (__attribute__((address_space(3))) uint32_t*)lds, 16, 0, 0);
}

// tile [128 rows][64 bf16=128B]; content XOR-swizzled by row
__device__ __forceinline__ bf16x8 lds_read8_swz(const u16* base, int row, int inner) {
    int off = row * 128 + (inner ^ ((row & 7) << 4));
    return *(const bf16x8*)((const char*)base + off);
}

__device__ __forceinline__ void route_body(const int* topk_ids, const float* topk_w,
                                           int* sched, int* row_token, float* row_w,
                                           int* cnt, int* off, int* cur) {
    const int tid = threadIdx.x;
    if (tid < NEXP) cnt[tid] = 0;
    __syncthreads();
    for (int p = tid; p < NROWS; p += blockDim.x)
        atomicAdd(&cnt[topk_ids[p]], 1);
    __syncthreads();
    if (tid == 0) {
        int acc = 0, mb = 0;
        for (int e = 0; e < NEXP; ++e) {
            off[e] = acc;
            int c = cnt[e];
            for (int m0 = 0; m0 < c; m0 += BM) {
                sched[1 + 3 * mb] = e;
                sched[2 + 3 * mb] = acc + m0;
                sched[3 + 3 * mb] = (c - m0 < BM) ? (c - m0) : BM;
                ++mb;
            }
            acc += c;
        }
        sched[0] = mb;
    }
    if (tid < NEXP) cur[tid] = 0;
    __syncthreads();
    for (int p = tid; p < NROWS; p += blockDim.x) {
        int e = topk_ids[p];
        int slot = off[e] + atomicAdd(&cur[e], 1);
        row_token[slot] = p / TOPK;
        row_w[slot]     = topk_w[p];
    }
}

// ---------------- prep_a: w1 + X -> bf16 (NT reads); zero out; route ---------
__global__ void prep_kernel(const float* __restrict__ w1, const float* __restrict__ X,
                            u16* __restrict__ w1b, u16* __restrict__ Xb,
                            float* __restrict__ out,
                            const int* __restrict__ topk_ids,
                            const float* __restrict__ topk_w,
                            int* __restrict__ sched, int* __restrict__ row_token,
                            float* __restrict__ row_w) {
    __shared__ int cnt[NEXP], off[NEXP], cur[NEXP];
    if (blockIdx.x == PREP_BLKS) {   // routing-only block
        route_body(topk_ids, topk_w, sched, row_token, row_w, cnt, off, cur);
        return;
    }
    const size_t stride = (size_t)PREP_BLKS * 256;
    for (size_t t = (size_t)blockIdx.x * 256 + threadIdx.x; t < PREP_CHUNKS_A; t += stride) {
        if (t < W1_T) {
            cvt8_nt(w1 + t * 8, w1b + t * 8);
        } else {
            size_t u = t - W1_T;
            cvt8_nt(X + u * 8, Xb + u * 8);
            f32x4 z = (f32x4){0.f, 0.f, 0.f, 0.f};
            *(f32x4*)(out + u * 8) = z;
            *(f32x4*)(out + u * 8 + 4) = z;
        }
    }
}

// XCD map: blocks sharing a B-tile (same e,n0; different m0) land on ONE XCD.
#define DECODE_BLOCK()                                                    \
    const int bid   = blockIdx.x;                                         \
    const int xcd   = bid & 7;                                            \
    const int local = bid >> 3;            /* 0..79 */                    \
    const int n0h   = local / MAX_MB;      /* 0..1  */                    \
    const int mb    = local - n0h * MAX_MB;                               \
    const int n0i   = xcd * 2 + n0h;       /* 0..15 */                    \
    if (mb >= sched[0]) return;                                           \
    const int e    = sched[1 + 3 * mb];                                   \
    const int m0   = sched[2 + 3 * mb];                                   \
    const int mlen = sched[3 + 3 * mb]

#define GLL8(k0)                                                          \
    _Pragma("unroll") for (int i = 0; i < 4; ++i)                         \
        gll16(asrc[i] + (k0), &lA[aoff[i]]);                              \
    _Pragma("unroll") for (int i = 0; i < 4; ++i)                         \
        gll16(bsrc[i] + (k0), &lB[aoff[i]]);

// ---------------- GEMM1 fast + w2-conversion worker blocks -------------------
__global__ __launch_bounds__(256, 3)
void gemm1p_kernel(const u16* __restrict__ Xb, const u16* __restrict__ w1b,
                   const int* __restrict__ sched, const int* __restrict__ row_token,
                   u16* __restrict__ H,
                   const float* __restrict__ w2f, u16* __restrict__ w2b) {
    __shared__ u16 lA[BM * BK];   // 16KB, gll (linear dest, pre-swz src)
    __shared__ u16 lB[BM * BK];   // 16KB, gll

    // w2-conversion workers: co-scheduled with MFMA blocks, stream under them.
    if (blockIdx.x >= GRID_G) {
        const size_t stride = (size_t)CVT2_BLKS * 256;
        for (size_t t = (size_t)(blockIdx.x - GRID_G) * 256 + threadIdx.x;
             t < W2_T; t += stride)
            cvt8_nt(w2f + t * 8, w2b + t * 8);
        return;
    }

    DECODE_BLOCK();
    const int n0 = n0i * 64;

    const int tid  = threadIdx.x;
    const int lane = tid & 63;
    const int wave = tid >> 6;
    const int wm = wave >> 1, wn = wave & 1;
    const int lr = lane & 15, lk = lane >> 4;

    const u16* asrc[4];
    const u16* bsrc[4];
    int aoff[4];
#pragma unroll
    for (int i = 0; i < 4; ++i) {
        int R = i * 32 + wave * 8 + (lane >> 3);
        int grow = m0 + R; if (grow > NROWS - 1) grow = NROWS - 1;
        int tok = row_token[grow];
        int c8 = ((lane & 7) ^ (R & 7)) * 8;
        asrc[i] = Xb + (size_t)tok * D_DIM + c8;
        int gr = (R < 64) ? (n0 + R) : (DFF_DIM + n0 + (R - 64));
        bsrc[i] = w1b + ((size_t)e * (2 * DFF_DIM) + gr) * D_DIM + c8;
        aoff[i] = i * 2048 + wave * 512;
    }

    f32x4 accg[4][2], accu[4][2];
#pragma unroll
    for (int m = 0; m < 4; ++m)
#pragma unroll
        for (int n = 0; n < 2; ++n) {
            accg[m][n] = (f32x4){0.f, 0.f, 0.f, 0.f};
            accu[m][n] = (f32x4){0.f, 0.f, 0.f, 0.f};
        }

    const int KT = D_DIM / BK;   // 32
    for (int kt = 0; kt < KT; ++kt) {
        GLL8(kt * BK);
        __syncthreads();   // drains glls (vmcnt 0)
#pragma unroll
        for (int ks = 0; ks < 2; ++ks) {
            const int inner = ks * 64 + lk * 16;
            bf16x8 af[4], bg[2], bu[2];
#pragma unroll
            for (int m = 0; m < 4; ++m)
                af[m] = lds_read8_swz(lA, wm * 64 + m * 16 + lr, inner);
#pragma unroll
            for (int n = 0; n < 2; ++n) {
                bg[n] = lds_read8_swz(lB, wn * 32 + n * 16 + lr, inner);
                bu[n] = lds_read8_swz(lB, 64 + wn * 32 + n * 16 + lr, inner);
            }
#pragma unroll
            for (int m = 0; m < 4; ++m)
#pragma unroll
                for (int n = 0; n < 2; ++n) {
                    accg[m][n] = __builtin_amdgcn_mfma_f32_16x16x32_bf16(af[m], bg[n], accg[m][n], 0, 0, 0);
                    accu[m][n] = __builtin_amdgcn_mfma_f32_16x16x32_bf16(af[m], bu[n], accu[m][n], 0, 0, 0);
                }
        }
        __syncthreads();   // reads done before next overwrite
    }

    // epilogue: h = silu(gate) * up
#pragma unroll
    for (int m = 0; m < 4; ++m)
#pragma unroll
        for (int n = 0; n < 2; ++n)
#pragma unroll
            for (int r = 0; r < 4; ++r) {
                int rloc = wm * 64 + m * 16 + (lane >> 4) * 4 + r;
                if (rloc < mlen) {
                    int col = wn * 32 + n * 16 + lr;
                    float g = accg[m][n][r], u = accu[m][n][r];
                    float h = (g / (1.f + __expf(-g))) * u;
                    H[(size_t)(m0 + rloc) * DFF_DIM + n0 + col] = f2bf(h);
                }
            }
}

// ---------------- GEMM2 fast: H @ w2b_e^T, scale, atomicAdd ------------------
__global__ __launch_bounds__(256, 3)
void gemm2p_kernel(const u16* __restrict__ H, const u16* __restrict__ w2b,
                   const int* __restrict__ sched, const int* __restrict__ row_token,
                   const float* __restrict__ row_w, float* __restrict__ out) {
    __shared__ u16 lA[BM * BK];
    __shared__ u16 lB[BM * BK];

    DECODE_BLOCK();
    const int n0 = n0i * 128;

    const int tid  = threadIdx.x;
    const int lane = tid & 63;
    const int wave = tid >> 6;
    const int wm = wave >> 1, wn = wave & 1;
    const int lr = lane & 15, lk = lane >> 4;

    const u16* asrc[4];
    const u16* bsrc[4];
    int aoff[4];
#pragma unroll
    for (int i = 0; i < 4; ++i) {
        int R = i * 32 + wave * 8 + (lane >> 3);
        int grow = m0 + R; if (grow > NROWS - 1) grow = NROWS - 1;
        int c8 = ((lane & 7) ^ (R & 7)) * 8;
        asrc[i] = H + (size_t)grow * DFF_DIM + c8;
        bsrc[i] = w2b + ((size_t)e * D_DIM + (n0 + R)) * DFF_DIM + c8;
        aoff[i] = i * 2048 + wave * 512;
    }

    f32x4 acc[4][4];
#pragma unroll
    for (int m = 0; m < 4; ++m)
#pragma unroll
        for (int n = 0; n < 4; ++n) acc[m][n] = (f32x4){0.f, 0.f, 0.f, 0.f};

    const int KT = DFF_DIM / BK;   // 16
    for (int kt = 0; kt < KT; ++kt) {
        GLL8(kt * BK);
        __syncthreads();
#pragma unroll
        for (int ks = 0; ks < 2; ++ks) {
            const int inner = ks * 64 + lk * 16;
            bf16x8 af[4], bfr[4];
#pragma unroll
            for (int m = 0; m < 4; ++m)
                af[m] = lds_read8_swz(lA, wm * 64 + m * 16 + lr, inner);
#pragma unroll
            for (int n = 0; n < 4; ++n)
                bfr[n] = lds_read8_swz(lB, wn * 64 + n * 16 + lr, inner);
#pragma unroll
            for (int m = 0; m < 4; ++m)
#pragma unroll
                for (int n = 0; n < 4; ++n)
                    acc[m][n] = __builtin_amdgcn_mfma_f32_16x16x32_bf16(af[m], bfr[n], acc[m][n], 0, 0, 0);
        }
        __syncthreads();
    }

#pragma unroll
    for (int m = 0; m < 4; ++m)
#pragma unroll
        for (int n = 0; n < 4; ++n)
#pragma unroll
            for (int r = 0; r < 4; ++r) {
                int rloc = wm * 64 + m * 16 + (lane >> 4) * 4 + r;
                if (rloc < mlen) {
                    int grow = m0 + rloc;
                    int tok  = row_token[grow];
                    float w  = row_w[grow];
                    int col  = wn * 64 + n * 16 + lr;
                    atomicAdd(&out[(size_t)tok * D_DIM + n0 + col], acc[m][n][r] * w);
                }
            }
}

// ======================= fallback path (ws too small) ========================
__global__ void cvt_x_kernel(const float* __restrict__ X, u16* __restrict__ Xb,
                             float* __restrict__ out) {
    int idx = (blockIdx.x * 256 + threadIdx.x) * 8;
    cvt8(X + idx, Xb + idx);
    f32x4 z = (f32x4){0.f, 0.f, 0.f, 0.f};
    *(f32x4*)(out + idx) = z;
    *(f32x4*)(out + idx + 4) = z;
}

__global__ void route_kernel(const int* __restrict__ topk_ids,
                             const float* __restrict__ topk_w,
                             int* __restrict__ sched,
                             int* __restrict__ row_token,
                             float* __restrict__ row_w) {
    __shared__ int cnt[NEXP], off[NEXP], cur[NEXP];
    route_body(topk_ids, topk_w, sched, row_token, row_w, cnt, off, cur);
}

#define GLL_A(k0, dst)                                                    \
    _Pragma("unroll") for (int i = 0; i < 4; ++i)                         \
        gll16(asrc[i] + (k0), &(dst)[aoff[i]]);

#define LOAD_RB(rb, k0)                                                   \
    _Pragma("unroll") for (int i = 0; i < 4; ++i) {                       \
        rb[i][0] = *(const f32x4*)(bptr[i] + (k0));                       \
        rb[i][1] = *(const f32x4*)(bptr[i] + (k0) + 4);                   \
    }

#define CVT_WRITE(rb, dst)                                                \
    _Pragma("unroll") for (int i = 0; i < 4; ++i) {                       \
        bf16x8 vb;                                                        \
        _Pragma("unroll") for (int j = 0; j < 4; ++j) {                   \
            vb[j] = (short)f2bf(rb[i][0][j]);                             \
            vb[j + 4] = (short)f2bf(rb[i][1][j]);                         \
        }                                                                 \
        *(bf16x8*)((char*)(dst) + wroff[i]) = vb;                         \
    }

__global__ __launch_bounds__(256, 3)
void gemm1f_kernel(const u16* __restrict__ Xb, const float* __restrict__ w1,
                   const int* __restrict__ sched, const int* __restrict__ row_token,
                   u16* __restrict__ H) {
    __shared__ u16 lA[2][BM * BK];
    __shared__ u16 lB[BM * BK];

    DECODE_BLOCK();
    const int n0 = n0i * 64;

    const int tid  = threadIdx.x;
    const int lane = tid & 63;
    const int wave = tid >> 6;
    const int wm = wave >> 1, wn = wave & 1;
    const int lr = lane & 15, lk = lane >> 4;

    const u16* asrc[4];
    int aoff[4];
#pragma unroll
    for (int i = 0; i < 4; ++i) {
        int R = i * 32 + wave * 8 + (lane >> 3);
        int grow = m0 + R; if (grow > NROWS - 1) grow = NROWS - 1;
        int tok = row_token[grow];
        asrc[i] = Xb + (size_t)tok * D_DIM + (size_t)(((lane & 7) ^ (R & 7)) * 8);
        aoff[i] = i * 2048 + wave * 512;
    }
    const float* bptr[4];
    int wroff[4];
#pragma unroll
    for (int i = 0; i < 4; ++i) {
        int chunk = i * 256 + tid;
        int row = chunk >> 3, c8 = chunk & 7;
        int gcol = (row < 64) ? (n0 + row) : (DFF_DIM + n0 + (row - 64));
        bptr[i] = w1 + ((size_t)e * (2 * DFF_DIM) + gcol) * D_DIM + c8 * 8;
        wroff[i] = row * 128 + ((c8 * 16) ^ ((row & 7) << 4));
    }

    f32x4 rb[4][2];
    f32x4 accg[4][2], accu[4][2];
#pragma unroll
    for (int m = 0; m < 4; ++m)
#pragma unroll
        for (int n = 0; n < 2; ++n) {
            accg[m][n] = (f32x4){0.f, 0.f, 0.f, 0.f};
            accu[m][n] = (f32x4){0.f, 0.f, 0.f, 0.f};
        }

#define MFMA_G1(bufA, bufB)                                               \
    _Pragma("unroll") for (int ks = 0; ks < 2; ++ks) {                    \
        const int inner = ks * 64 + lk * 16;                              \
        bf16x8 af[4], bg[2], bu[2];                                       \
        _Pragma("unroll") for (int m = 0; m < 4; ++m)                     \
            af[m] = lds_read8_swz(bufA, wm * 64 + m * 16 + lr, inner);    \
        _Pragma("unroll") for (int n = 0; n < 2; ++n) {                   \
            bg[n] = lds_read8_swz(bufB, wn * 32 + n * 16 + lr, inner);    \
            bu[n] = lds_read8_swz(bufB, 64 + wn * 32 + n * 16 + lr, inner); \
        }                                                                 \
        _Pragma("unroll") for (int m = 0; m < 4; ++m)                     \
            _Pragma("unroll") for (int n = 0; n < 2; ++n) {               \
                accg[m][n] = __builtin_amdgcn_mfma_f32_16x16x32_bf16(af[m], bg[n], accg[m][n], 0, 0, 0); \
                accu[m][n] = __builtin_amdgcn_mfma_f32_16x16x32_bf16(af[m], bu[n], accu[m][n], 0, 0, 0); \
            }                                                             \
    }

    const int KT = D_DIM / BK;
    LOAD_RB(rb, 0);
    GLL_A(0, lA[0]);
    CVT_WRITE(rb, lB);
    __syncthreads();

    for (int kt = 0, cur = 0; kt < KT; ++kt, cur ^= 1) {
        if (kt + 1 < KT) {
            LOAD_RB(rb, (kt + 1) * BK);
            GLL_A((kt + 1) * BK, lA[cur ^ 1]);
        }
        PIN();
        MFMA_G1(lA[cur], lB);
        BAR_LGKM();
        if (kt + 1 < KT) { CVT_WRITE(rb, lB); }
        __syncthreads();
    }
#undef MFMA_G1

#pragma unroll
    for (int m = 0; m < 4; ++m)
#pragma unroll
        for (int n = 0; n < 2; ++n)
#pragma unroll
            for (int r = 0; r < 4; ++r) {
                int rloc = wm * 64 + m * 16 + (lane >> 4) * 4 + r;
                if (rloc < mlen) {
                    int col = wn * 32 + n * 16 + lr;
                    float g = accg[m][n][r], u = accu[m][n][r];
                    float h = (g / (1.f + __expf(-g))) * u;
                    H[(size_t)(m0 + rloc) * DFF_DIM + n0 + col] = f2bf(h);
                }
            }
}

__global__ __launch_bounds__(256, 3)
void gemm2f_kernel(const u16* __restrict__ H, const float* __restrict__ w2,
                   const int* __restrict__ sched, const int* __restrict__ row_token,
                   const float* __restrict__ row_w, float* __restrict__ out) {
    __shared__ u16 lA[2][BM * BK];
    __shared__ u16 lB[BM * BK];

    DECODE_BLOCK();
    const int n0 = n0i * 128;

    const int tid  = threadIdx.x;
    const int lane = tid & 63;
    const int wave = tid >> 6;
    const int wm = wave >> 1, wn = wave & 1;
    const int lr = lane & 15, lk = lane >> 4;

    const u16* asrc[4];
    int aoff[4];
#pragma unroll
    for (int i = 0; i < 4; ++i) {
        int R = i * 32 + wave * 8 + (lane >> 3);
        int grow = m0 + R; if (grow > NROWS - 1) grow = NROWS - 1;
        asrc[i] = H + (size_t)grow * DFF_DIM + (size_t)(((lane & 7) ^ (R & 7)) * 8);
        aoff[i] = i * 2048 + wave * 512;
    }
    const float* bptr[4];
    int wroff[4];
#pragma unroll
    for (int i = 0; i < 4; ++i) {
        int chunk = i * 256 + tid;
        int row = chunk >> 3, c8 = chunk & 7;
        bptr[i] = w2 + ((size_t)e * D_DIM + (n0 + row)) * DFF_DIM + c8 * 8;
        wroff[i] = row * 128 + ((c8 * 16) ^ ((row & 7) << 4));
    }

    f32x4 rb[4][2];
    f32x4 acc[4][4];
#pragma unroll
    for (int m = 0; m < 4; ++m)
#pragma unroll
        for (int n = 0; n < 4; ++n) acc[m][n] = (f32x4){0.f, 0.f, 0.f, 0.f};

#define MFMA_G2(bufA, bufB)                                               \
    _Pragma("unroll") for (int ks = 0; ks < 2; ++ks) {                    \
        const int inner = ks * 64 + lk * 16;                              \
        bf16x8 af[4], bfr[4];                                             \
        _Pragma("unroll") for (int m = 0; m < 4; ++m)                     \
            af[m] = lds_read8_swz(bufA, wm * 64 + m * 16 + lr, inner);    \
        _Pragma("unroll") for (int n = 0; n < 4; ++n)                     \
            bfr[n] = lds_read8_swz(bufB, wn * 64 + n * 16 + lr, inner);   \
        _Pragma("unroll") for (int m = 0; m < 4; ++m)                     \
            _Pragma("unroll") for (int n = 0; n < 4; ++n)                 \
                acc[m][n] = __builtin_amdgcn_mfma_f32_16x16x32_bf16(af[m], bfr[n], acc[m][n], 0, 0, 0); \
    }

    const int KT = DFF_DIM / BK;
    LOAD_RB(rb, 0);
    GLL_A(0, lA[0]);
    CVT_WRITE(rb, lB);
    __syncthreads();

    for (int kt = 0, cur = 0; kt < KT; ++kt, cur ^= 1) {
        if (kt + 1 < KT) {
            LOAD_RB(rb, (kt + 1) * BK);
            GLL_A((kt + 1) * BK, lA[cur ^ 1]);
        }
        PIN();
        MFMA_G2(lA[cur], lB);
        BAR_LGKM();
        if (kt + 1 < KT) { CVT_WRITE(rb, lB); }
        __syncthreads();
    }
#undef MFMA_G2

#pragma unroll
    for (int m = 0; m < 4; ++m)
#pragma unroll
        for (int n = 0; n < 4; ++n)
#pragma unroll
            for (int r = 0; r < 4; ++r) {
                int rloc = wm * 64 + m * 16 + (lane >> 4) * 4 + r;
                if (rloc < mlen) {
                    int grow = m0 + rloc;
                    int tok  = row_token[grow];
                    float w  = row_w[grow];
                    int col  = wn * 64 + n * 16 + lr;
                    atomicAdd(&out[(size_t)tok * D_DIM + n0 + col], acc[m][n][r] * w);
                }
            }
}

extern "C" void kernel_launch(void* const* d_in, const int* in_sizes, int n_in,
                              void* d_out, int out_size, void* d_ws, size_t ws_size,
                              hipStream_t stream) {
    const float* X  = (const float*)d_in[0];
    const float* w1 = (const float*)d_in[1];
    const float* w2 = (const float*)d_in[2];
    const float* tw = (const float*)d_in[3];
    const int*   ti = (const int*)d_in[4];

    int*   sched     = (int*)d_ws;
    int*   row_token = (int*)((char*)d_ws + 512);
    float* row_w     = (float*)((char*)d_ws + 512 + 4 * NROWS);
    u16*   Xb        = (u16*)((char*)d_ws + XB_OFF);
    u16*   H         = (u16*)((char*)d_ws + H_OFF);

    if (ws_size >= WS_NEED) {
        u16* w1b = (u16*)((char*)d_ws + W1B_OFF);
        u16* w2b = (u16*)((char*)d_ws + W2B_OFF);
        prep_kernel<<<PREP_BLKS + 1, 256, 0, stream>>>(w1, X, w1b, Xb,
                                                       (float*)d_out, ti, tw,
                                                       sched, row_token, row_w);
        gemm1p_kernel<<<GRID_G + CVT2_BLKS, 256, 0, stream>>>(Xb, w1b, sched, row_token, H,
                                                              w2, w2b);
        gemm2p_kernel<<<GRID_G, 256, 0, stream>>>(H, w2b, sched, row_token, row_w, (float*)d_out);
    } else {
        route_kernel<<<1, 256, 0, stream>>>(ti, tw, sched, row_token, row_w);
        cvt_x_kernel<<<(T_TOK * D_DIM) / (256 * 8), 256, 0, stream>>>(X, Xb, (float*)d_out);
        gemm1f_kernel<<<GRID_G, 256, 0, stream>>>(Xb, w1, sched, row_token, H);
        gemm2f_kernel<<<GRID_G, 256, 0, stream>>>(H, w2, sched, row_token, row_w, (float*)d_out);
    }
}